// Round 3
// baseline (8758.973 us; speedup 1.0000x reference)
//
#include <hip/hip_runtime.h>
#include <math.h>

#define SEQ 4096
#define BATCH 8
#define NIN 1024
#define NH 256
#define NOUT 128
#define M (SEQ*BATCH)   // 32768

// ---------------- K1: xp = x @ W_xh + b_i2h  (M x NIN) @ (NIN x NH) ----------------
// grid: (M/64)*(NH/64) = 512*4 = 2048 blocks, 256 threads
__global__ __launch_bounds__(256) void k_xproj(const float* __restrict__ x,
                                               const float* __restrict__ Wi2h,
                                               const float* __restrict__ bi2h,
                                               float* __restrict__ xp) {
    __shared__ __align__(16) float At[32][64];  // transposed A tile [k][m]
    __shared__ __align__(16) float Bt[32][64];  // B tile [k][n]
    int bid = blockIdx.x;
    int bn_blk = bid & 3, bm_blk = bid >> 2;
    int m0 = bm_blk * 64, n0 = bn_blk * 64;
    int tid = threadIdx.x;
    int tx = tid & 15, ty = tid >> 4;           // compute mapping: rows ty*4.., cols tx*4..
    int lr = tid >> 3;                          // 0..31 (A load row)
    int lc = tid & 7;                           // 0..7  (A load col group, k)
    int bk = tid >> 4;                          // 0..15 (B load row, k)
    int bn = (tid & 15) * 4;                    // 0..60 (B load col)

    float acc[4][4];
    #pragma unroll
    for (int i = 0; i < 4; i++)
        #pragma unroll
        for (int j = 0; j < 4; j++) acc[i][j] = 0.f;

    for (int k0 = 0; k0 < NIN; k0 += 32) {
        float4 a0 = *(const float4*)&x[(size_t)(m0 + lr)      * NIN + k0 + lc * 4];
        float4 a1 = *(const float4*)&x[(size_t)(m0 + lr + 32) * NIN + k0 + lc * 4];
        float4 b0 = *(const float4*)&Wi2h[(size_t)(k0 + bk)      * NH + n0 + bn];
        float4 b1 = *(const float4*)&Wi2h[(size_t)(k0 + bk + 16) * NH + n0 + bn];
        __syncthreads();   // previous iteration's compute done before overwrite
        At[lc*4+0][lr] = a0.x; At[lc*4+1][lr] = a0.y; At[lc*4+2][lr] = a0.z; At[lc*4+3][lr] = a0.w;
        At[lc*4+0][lr+32] = a1.x; At[lc*4+1][lr+32] = a1.y; At[lc*4+2][lr+32] = a1.z; At[lc*4+3][lr+32] = a1.w;
        *(float4*)&Bt[bk][bn]      = b0;
        *(float4*)&Bt[bk+16][bn]   = b1;
        __syncthreads();
        #pragma unroll
        for (int kk = 0; kk < 32; kk++) {
            float4 av = *(const float4*)&At[kk][ty*4];
            float4 bv = *(const float4*)&Bt[kk][tx*4];
            float a[4] = {av.x, av.y, av.z, av.w};
            float b[4] = {bv.x, bv.y, bv.z, bv.w};
            #pragma unroll
            for (int i = 0; i < 4; i++)
                #pragma unroll
                for (int j = 0; j < 4; j++)
                    acc[i][j] = fmaf(a[i], b[j], acc[i][j]);
        }
    }
    float4 bb = *(const float4*)&bi2h[n0 + tx*4];
    float bias[4] = {bb.x, bb.y, bb.z, bb.w};
    #pragma unroll
    for (int i = 0; i < 4; i++) {
        float4 v = make_float4(acc[i][0] + bias[0], acc[i][1] + bias[1],
                               acc[i][2] + bias[2], acc[i][3] + bias[3]);
        *(float4*)&xp[(size_t)(m0 + ty*4 + i) * NH + n0 + tx*4] = v;
    }
}

// ---------------- K2: sequential scan, one block per batch ----------------
// 8 blocks (1 per batch), 512 threads = 8 waves.
// wave wv owns columns wv*32 .. wv*32+31; lane&31 = column offset; lane>>5 = k-half.
// Per step: 128 FMAs/thread (own k-half), in-wave k-reduce via shfl_xor(32),
// all waves tanh their own columns. ONE raw barrier per step (lgkmcnt only —
// hs store + xp prefetch stay in flight across it). Double-buffered h in LDS.
__global__ __launch_bounds__(512) void k_scan(const float* __restrict__ Wi2h,
                                              const float* __restrict__ h0,
                                              const float* __restrict__ xp,
                                              float* __restrict__ hs) {
    __shared__ __align__(16) float hbuf[2][NH];
    int b = blockIdx.x;
    int tid = threadIdx.x;
    int wv = tid >> 6;
    int lane = tid & 63;
    int cl = lane & 31;
    int kh = lane >> 5;            // 0: k 0..127, 1: k 128..255
    int col = wv * 32 + cl;

    // W_hh slice in registers: rows NIN + kh*128 + (0..127), column col (128 regs)
    float4 w[32];
    #pragma unroll
    for (int r = 0; r < 32; r++) {
        const float* base = &Wi2h[(size_t)(NIN + kh*128 + r*4) * NH + col];
        w[r].x = base[0*NH];
        w[r].y = base[1*NH];
        w[r].z = base[2*NH];
        w[r].w = base[3*NH];
    }

    if (tid < NH) hbuf[0][tid] = h0[b*NH + tid];
    float xc = xp[(size_t)(0*BATCH + b) * NH + col];
    __syncthreads();

    for (int t = 0; t < SEQ; t++) {
        const float* rb = &hbuf[t & 1][kh * 128];
        float*       wbuf = hbuf[(t + 1) & 1];
        float xn = 0.f;
        if (t + 1 < SEQ) xn = xp[(size_t)((t+1)*BATCH + b) * NH + col];

        float ax = 0.f, ay = 0.f, az = 0.f, aw = 0.f;
        #pragma unroll
        for (int r = 0; r < 32; r++) {
            float4 h4 = *(const float4*)&rb[r * 4];   // broadcast read (2 addrs/wave)
            ax = fmaf(h4.x, w[r].x, ax);
            ay = fmaf(h4.y, w[r].y, ay);
            az = fmaf(h4.z, w[r].z, az);
            aw = fmaf(h4.w, w[r].w, aw);
        }
        float s = (ax + ay) + (az + aw);
        s += __shfl_xor(s, 32, 64);   // add other k-half's partial
        s += xc;
        float hn = tanhf(s);
        if (kh == 0) wbuf[col] = hn;                                   // LDS for next step
        else         hs[(size_t)(t*BATCH + b) * NH + col] = hn;        // global, not drained
        xc = xn;

        // raw barrier: wait LDS only — global store/load stay in flight
        asm volatile("s_waitcnt lgkmcnt(0)" ::: "memory");
        __builtin_amdgcn_s_barrier();
        asm volatile("" ::: "memory");
    }
}

// ---------------- K3: out = hs @ W_h2o + b_h2o  (M x NH) @ (NH x NOUT) ----------------
// grid: (M/128 row tiles) * 2 col-halves = 512 blocks, 256 threads
__global__ __launch_bounds__(256) void k_out(const float* __restrict__ hs,
                                             const float* __restrict__ Wh2o,
                                             const float* __restrict__ bh2o,
                                             float* __restrict__ out) {
    __shared__ float Wl[NH][64];   // 64 KB: W_h2o columns half*64..+63
    __shared__ float Hl[8][NH];    // 8 KB
    int bid = blockIdx.x;
    int half = bid & 1;
    int rt = bid >> 1;             // 0..255 -> rows rt*128..+127
    int tid = threadIdx.x;

    for (int i = tid; i < NH*64; i += 256) {
        int k = i >> 6, o = i & 63;
        Wl[k][o] = Wh2o[(size_t)k*NOUT + half*64 + o];
    }
    int o = tid & 63, g = tid >> 6;   // g = 0..3, rows g*2, g*2+1 within tile
    float bias = bh2o[half*64 + o];

    for (int tile = 0; tile < 16; tile++) {
        int r0 = rt*128 + tile*8;
        __syncthreads();   // W staged (tile 0) / previous tile compute done
        for (int i = tid; i < 8*NH; i += 256)
            Hl[i >> 8][i & 255] = hs[(size_t)r0*NH + i];
        __syncthreads();
        float a0 = 0.f, a1 = 0.f;
        int r = g * 2;
        #pragma unroll 8
        for (int k = 0; k < NH; k++) {
            float wv = Wl[k][o];
            a0 = fmaf(Hl[r][k],   wv, a0);
            a1 = fmaf(Hl[r+1][k], wv, a1);
        }
        out[(size_t)(r0 + r)     * NOUT + half*64 + o] = a0 + bias;
        out[(size_t)(r0 + r + 1) * NOUT + half*64 + o] = a1 + bias;
    }
}

extern "C" void kernel_launch(void* const* d_in, const int* in_sizes, int n_in,
                              void* d_out, int out_size, void* d_ws, size_t ws_size,
                              hipStream_t stream) {
    const float* x    = (const float*)d_in[0];
    const float* h0   = (const float*)d_in[1];
    const float* Wi2h = (const float*)d_in[2];
    const float* bi2h = (const float*)d_in[3];
    const float* Wh2o = (const float*)d_in[4];
    const float* bh2o = (const float*)d_in[5];
    float* out = (float*)d_out;

    float* xp = (float*)d_ws;                     // M*NH f32 = 32 MB
    float* hs = xp + (size_t)M * NH;              // M*NH f32 = 32 MB

    k_xproj<<<dim3(2048), dim3(256), 0, stream>>>(x, Wi2h, bi2h, xp);
    k_scan <<<dim3(BATCH), dim3(512), 0, stream>>>(Wi2h, h0, xp, hs);
    k_out  <<<dim3(512), dim3(256), 0, stream>>>(hs, Wh2o, bh2o, out);
}

// Round 4
// 2984.978 us; speedup vs baseline: 2.9344x; 2.9344x over previous
//
#include <hip/hip_runtime.h>
#include <math.h>

#define SEQ 4096
#define BATCH 8
#define NIN 1024
#define NH 256
#define NOUT 128
#define M (SEQ*BATCH)   // 32768

// ---------------- K1: xp = x @ W_xh + b_i2h  (M x NIN) @ (NIN x NH) ----------------
__global__ __launch_bounds__(256) void k_xproj(const float* __restrict__ x,
                                               const float* __restrict__ Wi2h,
                                               const float* __restrict__ bi2h,
                                               float* __restrict__ xp) {
    __shared__ __align__(16) float At[32][64];
    __shared__ __align__(16) float Bt[32][64];
    int bid = blockIdx.x;
    int bn_blk = bid & 3, bm_blk = bid >> 2;
    int m0 = bm_blk * 64, n0 = bn_blk * 64;
    int tid = threadIdx.x;
    int tx = tid & 15, ty = tid >> 4;
    int lr = tid >> 3;
    int lc = tid & 7;
    int bk = tid >> 4;
    int bn = (tid & 15) * 4;

    float acc[4][4];
    #pragma unroll
    for (int i = 0; i < 4; i++)
        #pragma unroll
        for (int j = 0; j < 4; j++) acc[i][j] = 0.f;

    for (int k0 = 0; k0 < NIN; k0 += 32) {
        float4 a0 = *(const float4*)&x[(size_t)(m0 + lr)      * NIN + k0 + lc * 4];
        float4 a1 = *(const float4*)&x[(size_t)(m0 + lr + 32) * NIN + k0 + lc * 4];
        float4 b0 = *(const float4*)&Wi2h[(size_t)(k0 + bk)      * NH + n0 + bn];
        float4 b1 = *(const float4*)&Wi2h[(size_t)(k0 + bk + 16) * NH + n0 + bn];
        __syncthreads();
        At[lc*4+0][lr] = a0.x; At[lc*4+1][lr] = a0.y; At[lc*4+2][lr] = a0.z; At[lc*4+3][lr] = a0.w;
        At[lc*4+0][lr+32] = a1.x; At[lc*4+1][lr+32] = a1.y; At[lc*4+2][lr+32] = a1.z; At[lc*4+3][lr+32] = a1.w;
        *(float4*)&Bt[bk][bn]      = b0;
        *(float4*)&Bt[bk+16][bn]   = b1;
        __syncthreads();
        #pragma unroll
        for (int kk = 0; kk < 32; kk++) {
            float4 av = *(const float4*)&At[kk][ty*4];
            float4 bv = *(const float4*)&Bt[kk][tx*4];
            float a[4] = {av.x, av.y, av.z, av.w};
            float b[4] = {bv.x, bv.y, bv.z, bv.w};
            #pragma unroll
            for (int i = 0; i < 4; i++)
                #pragma unroll
                for (int j = 0; j < 4; j++)
                    acc[i][j] = fmaf(a[i], b[j], acc[i][j]);
        }
    }
    float4 bb = *(const float4*)&bi2h[n0 + tx*4];
    float bias[4] = {bb.x, bb.y, bb.z, bb.w};
    #pragma unroll
    for (int i = 0; i < 4; i++) {
        float4 v = make_float4(acc[i][0] + bias[0], acc[i][1] + bias[1],
                               acc[i][2] + bias[2], acc[i][3] + bias[3]);
        *(float4*)&xp[(size_t)(m0 + ty*4 + i) * NH + n0 + tx*4] = v;
    }
}

// ---------------- K2: sequential scan, one block per batch ----------------
// 512 threads = 8 waves. Thread (cb = tid>>3, kb = tid&7):
//   owns 4 columns (4cb..4cb+3) x 32 k-rows (32kb..32kb+31).
//   Weights (4x32 = 128 f32) in REGISTERS -> launch_bounds(512,2) allows 256 VGPR.
//   LDS h-reads: 8 x ds_read_b128, bank-staggered by (j+kb)&7 (conflict-free).
//   Cross-kb reduce: 4 shfl_xor (select-fold). Lane ends owning column
//   colf = 4cb + 2*(kb&1) + ((kb>>1)&1); kb<4 writes LDS h, kb>=4 writes hs (global).
//   ONE lgkm-only barrier per step: hs store + xp prefetch never drained.
__global__ __launch_bounds__(512, 2) void k_scan(const float* __restrict__ Wi2h,
                                                 const float* __restrict__ h0,
                                                 const float* __restrict__ xp,
                                                 float* __restrict__ hs) {
    __shared__ __align__(16) float hbuf[2][NH];
    int b = blockIdx.x;
    int tid = threadIdx.x;
    int cb = tid >> 3;            // 0..63  -> columns 4cb..4cb+3
    int kb = tid & 7;             // 0..7   -> k rows 32kb..32kb+31
    int b0 = kb & 1, b1 = (kb >> 1) & 1;
    int colf = 4*cb + (b0 << 1) + b1;    // final owned column after reduce

    // Weight registers: w4[c][j] = W_hh[32kb + 4*((j+kb)&7) + e][4cb+c]
    float4 w4[4][8];
    #pragma unroll
    for (int c = 0; c < 4; c++) {
        #pragma unroll
        for (int j = 0; j < 8; j++) {
            int kk = 32*kb + 4*((j + kb) & 7);
            const float* base = &Wi2h[(size_t)(NIN + kk) * NH + 4*cb + c];
            w4[c][j].x = base[0*NH];
            w4[c][j].y = base[1*NH];
            w4[c][j].z = base[2*NH];
            w4[c][j].w = base[3*NH];
        }
    }

    if (tid < NH) hbuf[0][tid] = h0[b*NH + tid];
    float xc = xp[(size_t)(0*BATCH + b) * NH + colf];
    __syncthreads();

    for (int t = 0; t < SEQ; t++) {
        const float* rb = &hbuf[t & 1][32 * kb];
        float xn = 0.f;
        if (t + 1 < SEQ) xn = xp[(size_t)((t+1)*BATCH + b) * NH + colf];

        // load h chunk (bank-staggered) and FMA into 4 column accumulators
        float4 hv[8];
        #pragma unroll
        for (int j = 0; j < 8; j++)
            hv[j] = *(const float4*)&rb[4 * ((j + kb) & 7)];

        float a0 = 0.f, a1 = 0.f, a2 = 0.f, a3 = 0.f;
        #pragma unroll
        for (int j = 0; j < 8; j++) {
            a0 = fmaf(hv[j].x, w4[0][j].x, a0); a0 = fmaf(hv[j].y, w4[0][j].y, a0);
            a0 = fmaf(hv[j].z, w4[0][j].z, a0); a0 = fmaf(hv[j].w, w4[0][j].w, a0);
            a1 = fmaf(hv[j].x, w4[1][j].x, a1); a1 = fmaf(hv[j].y, w4[1][j].y, a1);
            a1 = fmaf(hv[j].z, w4[1][j].z, a1); a1 = fmaf(hv[j].w, w4[1][j].w, a1);
            a2 = fmaf(hv[j].x, w4[2][j].x, a2); a2 = fmaf(hv[j].y, w4[2][j].y, a2);
            a2 = fmaf(hv[j].z, w4[2][j].z, a2); a2 = fmaf(hv[j].w, w4[2][j].w, a2);
            a3 = fmaf(hv[j].x, w4[3][j].x, a3); a3 = fmaf(hv[j].y, w4[3][j].y, a3);
            a3 = fmaf(hv[j].z, w4[3][j].z, a3); a3 = fmaf(hv[j].w, w4[3][j].w, a3);
        }

        // select-fold reduction over kb lanes (xor 1, 2, 4) — 4 shfls
        bool s0 = (kb & 1) != 0, s1 = (kb & 2) != 0;
        float k0v = s0 ? a2 : a0, k1v = s0 ? a3 : a1;
        float d0  = s0 ? a0 : a2, d1  = s0 ? a1 : a3;
        k0v += __shfl_xor(d0, 1, 64);
        k1v += __shfl_xor(d1, 1, 64);
        float ke = s1 ? k1v : k0v;
        float de = s1 ? k0v : k1v;
        ke += __shfl_xor(de, 2, 64);
        ke += __shfl_xor(ke, 4, 64);

        float s = ke + xc;
        // tanh via (z-1)/(z+1), z = exp2(2*log2(e)*s)
        float arg = s * 2.88539004f;
        float z;
        asm("v_exp_f32 %0, %1" : "=v"(z) : "v"(arg));
        float inv;
        float den = z + 1.0f;
        asm("v_rcp_f32 %0, %1" : "=v"(inv) : "v"(den));
        float hn = (z - 1.0f) * inv;

        if ((kb & 4) == 0) hbuf[(t + 1) & 1][colf] = hn;               // LDS for next step
        else               hs[(size_t)(t*BATCH + b) * NH + colf] = hn; // global, stays in flight
        xc = xn;

        asm volatile("s_waitcnt lgkmcnt(0)" ::: "memory");
        __builtin_amdgcn_s_barrier();
        asm volatile("" ::: "memory");
    }
}

// ---------------- K3: out = hs @ W_h2o + b_h2o ----------------
__global__ __launch_bounds__(256) void k_out(const float* __restrict__ hs,
                                             const float* __restrict__ Wh2o,
                                             const float* __restrict__ bh2o,
                                             float* __restrict__ out) {
    __shared__ float Wl[NH][64];
    __shared__ float Hl[8][NH];
    int bid = blockIdx.x;
    int half = bid & 1;
    int rt = bid >> 1;
    int tid = threadIdx.x;

    for (int i = tid; i < NH*64; i += 256) {
        int k = i >> 6, o = i & 63;
        Wl[k][o] = Wh2o[(size_t)k*NOUT + half*64 + o];
    }
    int o = tid & 63, g = tid >> 6;
    float bias = bh2o[half*64 + o];

    for (int tile = 0; tile < 16; tile++) {
        int r0 = rt*128 + tile*8;
        __syncthreads();
        for (int i = tid; i < 8*NH; i += 256)
            Hl[i >> 8][i & 255] = hs[(size_t)r0*NH + i];
        __syncthreads();
        float a0 = 0.f, a1 = 0.f;
        int r = g * 2;
        #pragma unroll 8
        for (int k = 0; k < NH; k++) {
            float wv = Wl[k][o];
            a0 = fmaf(Hl[r][k],   wv, a0);
            a1 = fmaf(Hl[r+1][k], wv, a1);
        }
        out[(size_t)(r0 + r)     * NOUT + half*64 + o] = a0 + bias;
        out[(size_t)(r0 + r + 1) * NOUT + half*64 + o] = a1 + bias;
    }
}

extern "C" void kernel_launch(void* const* d_in, const int* in_sizes, int n_in,
                              void* d_out, int out_size, void* d_ws, size_t ws_size,
                              hipStream_t stream) {
    const float* x    = (const float*)d_in[0];
    const float* h0   = (const float*)d_in[1];
    const float* Wi2h = (const float*)d_in[2];
    const float* bi2h = (const float*)d_in[3];
    const float* Wh2o = (const float*)d_in[4];
    const float* bh2o = (const float*)d_in[5];
    float* out = (float*)d_out;

    float* xp = (float*)d_ws;                     // M*NH f32 = 32 MB
    float* hs = xp + (size_t)M * NH;              // M*NH f32 = 32 MB

    k_xproj<<<dim3(2048), dim3(256), 0, stream>>>(x, Wi2h, bi2h, xp);
    k_scan <<<dim3(BATCH), dim3(512), 0, stream>>>(Wi2h, h0, xp, hs);
    k_out  <<<dim3(512), dim3(256), 0, stream>>>(hs, Wh2o, bh2o, out);
}

// Round 5
// 2843.631 us; speedup vs baseline: 3.0802x; 1.0497x over previous
//
#include <hip/hip_runtime.h>
#include <math.h>

#define SEQ 4096
#define BATCH 8
#define NIN 1024
#define NH 256
#define NOUT 128
#define M (SEQ*BATCH)   // 32768

// ---------------- K1: xp = x @ W_xh + b_i2h  (M x NIN) @ (NIN x NH) ----------------
__global__ __launch_bounds__(256) void k_xproj(const float* __restrict__ x,
                                               const float* __restrict__ Wi2h,
                                               const float* __restrict__ bi2h,
                                               float* __restrict__ xp) {
    __shared__ __align__(16) float At[32][64];
    __shared__ __align__(16) float Bt[32][64];
    int bid = blockIdx.x;
    int bn_blk = bid & 3, bm_blk = bid >> 2;
    int m0 = bm_blk * 64, n0 = bn_blk * 64;
    int tid = threadIdx.x;
    int tx = tid & 15, ty = tid >> 4;
    int lr = tid >> 3;
    int lc = tid & 7;
    int bk = tid >> 4;
    int bn = (tid & 15) * 4;

    float acc[4][4];
    #pragma unroll
    for (int i = 0; i < 4; i++)
        #pragma unroll
        for (int j = 0; j < 4; j++) acc[i][j] = 0.f;

    for (int k0 = 0; k0 < NIN; k0 += 32) {
        float4 a0 = *(const float4*)&x[(size_t)(m0 + lr)      * NIN + k0 + lc * 4];
        float4 a1 = *(const float4*)&x[(size_t)(m0 + lr + 32) * NIN + k0 + lc * 4];
        float4 b0 = *(const float4*)&Wi2h[(size_t)(k0 + bk)      * NH + n0 + bn];
        float4 b1 = *(const float4*)&Wi2h[(size_t)(k0 + bk + 16) * NH + n0 + bn];
        __syncthreads();
        At[lc*4+0][lr] = a0.x; At[lc*4+1][lr] = a0.y; At[lc*4+2][lr] = a0.z; At[lc*4+3][lr] = a0.w;
        At[lc*4+0][lr+32] = a1.x; At[lc*4+1][lr+32] = a1.y; At[lc*4+2][lr+32] = a1.z; At[lc*4+3][lr+32] = a1.w;
        *(float4*)&Bt[bk][bn]      = b0;
        *(float4*)&Bt[bk+16][bn]   = b1;
        __syncthreads();
        #pragma unroll
        for (int kk = 0; kk < 32; kk++) {
            float4 av = *(const float4*)&At[kk][ty*4];
            float4 bv = *(const float4*)&Bt[kk][tx*4];
            float a[4] = {av.x, av.y, av.z, av.w};
            float b[4] = {bv.x, bv.y, bv.z, bv.w};
            #pragma unroll
            for (int i = 0; i < 4; i++)
                #pragma unroll
                for (int j = 0; j < 4; j++)
                    acc[i][j] = fmaf(a[i], b[j], acc[i][j]);
        }
    }
    float4 bb = *(const float4*)&bi2h[n0 + tx*4];
    float bias[4] = {bb.x, bb.y, bb.z, bb.w};
    #pragma unroll
    for (int i = 0; i < 4; i++) {
        float4 v = make_float4(acc[i][0] + bias[0], acc[i][1] + bias[1],
                               acc[i][2] + bias[2], acc[i][3] + bias[3]);
        *(float4*)&xp[(size_t)(m0 + ty*4 + i) * NH + n0 + tx*4] = v;
    }
}

// ---------------- K2: sequential scan, one block per batch ----------------
// 512 threads = 8 waves. Thread (cb = tid>>3, kb = tid&7):
//   owns 4 columns (4cb..4cb+3) x 32 k-rows (32kb..32kb+31).
//   Weights (4x32 = 128 f32) in REGISTERS.
//   amdgpu_waves_per_eu(2,2): pin occupancy target to 2 waves/EU (1 WG/CU) so the
//   allocator's budget is 256 VGPR — grid is only 8 blocks, extra occupancy is useless.
//   (Round-4 evidence: without max pin, backend targeted 6 waves/EU -> 84 VGPR + scratch spill.)
//   LDS h-reads: 8 x ds_read_b128, bank-staggered by (j+kb)&7 (conflict-free).
//   Cross-kb reduce: 4 shfl_xor (select-fold). Lane ends owning column
//   colf = 4cb + 2*(kb&1) + ((kb>>1)&1); kb<4 writes LDS h, kb>=4 writes hs (global).
//   ONE lgkm-only barrier per step: hs store + xp prefetch never drained.
__global__ __launch_bounds__(512) __attribute__((amdgpu_waves_per_eu(2, 2)))
void k_scan(const float* __restrict__ Wi2h,
            const float* __restrict__ h0,
            const float* __restrict__ xp,
            float* __restrict__ hs) {
    __shared__ __align__(16) float hbuf[2][NH];
    int b = blockIdx.x;
    int tid = threadIdx.x;
    int cb = tid >> 3;            // 0..63  -> columns 4cb..4cb+3
    int kb = tid & 7;             // 0..7   -> k rows 32kb..32kb+31
    int b0 = kb & 1, b1 = (kb >> 1) & 1;
    int colf = 4*cb + (b0 << 1) + b1;    // final owned column after reduce

    // Weight registers: w4[c][j] = W_hh[32kb + 4*((j+kb)&7) + e][4cb+c]
    float4 w4[4][8];
    #pragma unroll
    for (int c = 0; c < 4; c++) {
        #pragma unroll
        for (int j = 0; j < 8; j++) {
            int kk = 32*kb + 4*((j + kb) & 7);
            const float* base = &Wi2h[(size_t)(NIN + kk) * NH + 4*cb + c];
            w4[c][j].x = base[0*NH];
            w4[c][j].y = base[1*NH];
            w4[c][j].z = base[2*NH];
            w4[c][j].w = base[3*NH];
        }
    }

    if (tid < NH) hbuf[0][tid] = h0[b*NH + tid];
    float xc = xp[(size_t)(0*BATCH + b) * NH + colf];
    __syncthreads();

    for (int t = 0; t < SEQ; t++) {
        const float* rb = &hbuf[t & 1][32 * kb];
        float xn = 0.f;
        if (t + 1 < SEQ) xn = xp[(size_t)((t+1)*BATCH + b) * NH + colf];

        // load h chunk (bank-staggered) and FMA into 4 column accumulators
        float4 hv[8];
        #pragma unroll
        for (int j = 0; j < 8; j++)
            hv[j] = *(const float4*)&rb[4 * ((j + kb) & 7)];

        float a0 = 0.f, a1 = 0.f, a2 = 0.f, a3 = 0.f;
        #pragma unroll
        for (int j = 0; j < 8; j++) {
            a0 = fmaf(hv[j].x, w4[0][j].x, a0); a0 = fmaf(hv[j].y, w4[0][j].y, a0);
            a0 = fmaf(hv[j].z, w4[0][j].z, a0); a0 = fmaf(hv[j].w, w4[0][j].w, a0);
            a1 = fmaf(hv[j].x, w4[1][j].x, a1); a1 = fmaf(hv[j].y, w4[1][j].y, a1);
            a1 = fmaf(hv[j].z, w4[1][j].z, a1); a1 = fmaf(hv[j].w, w4[1][j].w, a1);
            a2 = fmaf(hv[j].x, w4[2][j].x, a2); a2 = fmaf(hv[j].y, w4[2][j].y, a2);
            a2 = fmaf(hv[j].z, w4[2][j].z, a2); a2 = fmaf(hv[j].w, w4[2][j].w, a2);
            a3 = fmaf(hv[j].x, w4[3][j].x, a3); a3 = fmaf(hv[j].y, w4[3][j].y, a3);
            a3 = fmaf(hv[j].z, w4[3][j].z, a3); a3 = fmaf(hv[j].w, w4[3][j].w, a3);
        }

        // select-fold reduction over kb lanes (xor 1, 2, 4) — 4 shfls
        bool s0 = (kb & 1) != 0, s1 = (kb & 2) != 0;
        float k0v = s0 ? a2 : a0, k1v = s0 ? a3 : a1;
        float d0  = s0 ? a0 : a2, d1  = s0 ? a1 : a3;
        k0v += __shfl_xor(d0, 1, 64);
        k1v += __shfl_xor(d1, 1, 64);
        float ke = s1 ? k1v : k0v;
        float de = s1 ? k0v : k1v;
        ke += __shfl_xor(de, 2, 64);
        ke += __shfl_xor(ke, 4, 64);

        float s = ke + xc;
        // tanh via (z-1)/(z+1), z = exp2(2*log2(e)*s)
        float arg = s * 2.88539004f;
        float z;
        asm("v_exp_f32 %0, %1" : "=v"(z) : "v"(arg));
        float inv;
        float den = z + 1.0f;
        asm("v_rcp_f32 %0, %1" : "=v"(inv) : "v"(den));
        float hn = (z - 1.0f) * inv;

        if ((kb & 4) == 0) hbuf[(t + 1) & 1][colf] = hn;               // LDS for next step
        else               hs[(size_t)(t*BATCH + b) * NH + colf] = hn; // global, stays in flight
        xc = xn;

        asm volatile("s_waitcnt lgkmcnt(0)" ::: "memory");
        __builtin_amdgcn_s_barrier();
        asm volatile("" ::: "memory");
    }
}

// ---------------- K3: out = hs @ W_h2o + b_h2o ----------------
__global__ __launch_bounds__(256) void k_out(const float* __restrict__ hs,
                                             const float* __restrict__ Wh2o,
                                             const float* __restrict__ bh2o,
                                             float* __restrict__ out) {
    __shared__ float Wl[NH][64];
    __shared__ float Hl[8][NH];
    int bid = blockIdx.x;
    int half = bid & 1;
    int rt = bid >> 1;
    int tid = threadIdx.x;

    for (int i = tid; i < NH*64; i += 256) {
        int k = i >> 6, o = i & 63;
        Wl[k][o] = Wh2o[(size_t)k*NOUT + half*64 + o];
    }
    int o = tid & 63, g = tid >> 6;
    float bias = bh2o[half*64 + o];

    for (int tile = 0; tile < 16; tile++) {
        int r0 = rt*128 + tile*8;
        __syncthreads();
        for (int i = tid; i < 8*NH; i += 256)
            Hl[i >> 8][i & 255] = hs[(size_t)r0*NH + i];
        __syncthreads();
        float a0 = 0.f, a1 = 0.f;
        int r = g * 2;
        #pragma unroll 8
        for (int k = 0; k < NH; k++) {
            float wv = Wl[k][o];
            a0 = fmaf(Hl[r][k],   wv, a0);
            a1 = fmaf(Hl[r+1][k], wv, a1);
        }
        out[(size_t)(r0 + r)     * NOUT + half*64 + o] = a0 + bias;
        out[(size_t)(r0 + r + 1) * NOUT + half*64 + o] = a1 + bias;
    }
}

extern "C" void kernel_launch(void* const* d_in, const int* in_sizes, int n_in,
                              void* d_out, int out_size, void* d_ws, size_t ws_size,
                              hipStream_t stream) {
    const float* x    = (const float*)d_in[0];
    const float* h0   = (const float*)d_in[1];
    const float* Wi2h = (const float*)d_in[2];
    const float* bi2h = (const float*)d_in[3];
    const float* Wh2o = (const float*)d_in[4];
    const float* bh2o = (const float*)d_in[5];
    float* out = (float*)d_out;

    float* xp = (float*)d_ws;                     // M*NH f32 = 32 MB
    float* hs = xp + (size_t)M * NH;              // M*NH f32 = 32 MB

    k_xproj<<<dim3(2048), dim3(256), 0, stream>>>(x, Wi2h, bi2h, xp);
    k_scan <<<dim3(BATCH), dim3(512), 0, stream>>>(Wi2h, h0, xp, hs);
    k_out  <<<dim3(512), dim3(256), 0, stream>>>(hs, Wh2o, bh2o, out);
}

// Round 6
// 2687.799 us; speedup vs baseline: 3.2588x; 1.0580x over previous
//
#include <hip/hip_runtime.h>
#include <math.h>

#define SEQ 4096
#define BATCH 8
#define NIN 1024
#define NH 256
#define NOUT 128
#define M (SEQ*BATCH)   // 32768

// ---------------- K1: xp = x @ W_xh + b_i2h  (M x NIN) @ (NIN x NH) ----------------
__global__ __launch_bounds__(256) void k_xproj(const float* __restrict__ x,
                                               const float* __restrict__ Wi2h,
                                               const float* __restrict__ bi2h,
                                               float* __restrict__ xp) {
    __shared__ __align__(16) float At[32][64];
    __shared__ __align__(16) float Bt[32][64];
    int bid = blockIdx.x;
    int bn_blk = bid & 3, bm_blk = bid >> 2;
    int m0 = bm_blk * 64, n0 = bn_blk * 64;
    int tid = threadIdx.x;
    int tx = tid & 15, ty = tid >> 4;
    int lr = tid >> 3;
    int lc = tid & 7;
    int bk = tid >> 4;
    int bn = (tid & 15) * 4;

    float acc[4][4];
    #pragma unroll
    for (int i = 0; i < 4; i++)
        #pragma unroll
        for (int j = 0; j < 4; j++) acc[i][j] = 0.f;

    for (int k0 = 0; k0 < NIN; k0 += 32) {
        float4 a0 = *(const float4*)&x[(size_t)(m0 + lr)      * NIN + k0 + lc * 4];
        float4 a1 = *(const float4*)&x[(size_t)(m0 + lr + 32) * NIN + k0 + lc * 4];
        float4 b0 = *(const float4*)&Wi2h[(size_t)(k0 + bk)      * NH + n0 + bn];
        float4 b1 = *(const float4*)&Wi2h[(size_t)(k0 + bk + 16) * NH + n0 + bn];
        __syncthreads();
        At[lc*4+0][lr] = a0.x; At[lc*4+1][lr] = a0.y; At[lc*4+2][lr] = a0.z; At[lc*4+3][lr] = a0.w;
        At[lc*4+0][lr+32] = a1.x; At[lc*4+1][lr+32] = a1.y; At[lc*4+2][lr+32] = a1.z; At[lc*4+3][lr+32] = a1.w;
        *(float4*)&Bt[bk][bn]      = b0;
        *(float4*)&Bt[bk+16][bn]   = b1;
        __syncthreads();
        #pragma unroll
        for (int kk = 0; kk < 32; kk++) {
            float4 av = *(const float4*)&At[kk][ty*4];
            float4 bv = *(const float4*)&Bt[kk][tx*4];
            float a[4] = {av.x, av.y, av.z, av.w};
            float b[4] = {bv.x, bv.y, bv.z, bv.w};
            #pragma unroll
            for (int i = 0; i < 4; i++)
                #pragma unroll
                for (int j = 0; j < 4; j++)
                    acc[i][j] = fmaf(a[i], b[j], acc[i][j]);
        }
    }
    float4 bb = *(const float4*)&bi2h[n0 + tx*4];
    float bias[4] = {bb.x, bb.y, bb.z, bb.w};
    #pragma unroll
    for (int i = 0; i < 4; i++) {
        float4 v = make_float4(acc[i][0] + bias[0], acc[i][1] + bias[1],
                               acc[i][2] + bias[2], acc[i][3] + bias[3]);
        *(float4*)&xp[(size_t)(m0 + ty*4 + i) * NH + n0 + tx*4] = v;
    }
}

// ---------------- K2: sequential scan, one block per batch ----------------
// 512 threads = 8 waves. Thread (cb = tid>>3, kb = tid&7):
//   owns 4 columns (4cb..4cb+3) x 32 k-rows (32kb..32kb+31).
//   Weights (4x32 = 128 f32) preloaded, then LAUNDERED through empty inline asm
//   ("+v") so LLVM cannot rematerialize the Wi2h loads inside the loop
//   (round-5 evidence: VGPR=92, loads re-issued per step from L2).
//   amdgpu_waves_per_eu(2,2): budget 256 VGPR; grid is 8 blocks, occupancy
//   beyond 1 WG/CU is worthless.
__global__ __launch_bounds__(512) __attribute__((amdgpu_waves_per_eu(2, 2)))
void k_scan(const float* __restrict__ Wi2h,
            const float* __restrict__ h0,
            const float* __restrict__ xp,
            float* __restrict__ hs) {
    __shared__ __align__(16) float hbuf[2][NH];
    int b = blockIdx.x;
    int tid = threadIdx.x;
    int cb = tid >> 3;            // 0..63  -> columns 4cb..4cb+3
    int kb = tid & 7;             // 0..7   -> k rows 32kb..32kb+31
    int b0 = kb & 1, b1 = (kb >> 1) & 1;
    int colf = 4*cb + (b0 << 1) + b1;    // final owned column after reduce

    // Weight registers: w4[c][j] = W_hh[32kb + 4*((j+kb)&7) + e][4cb+c]
    float4 w4[4][8];
    #pragma unroll
    for (int c = 0; c < 4; c++) {
        #pragma unroll
        for (int j = 0; j < 8; j++) {
            int kk = 32*kb + 4*((j + kb) & 7);
            const float* base = &Wi2h[(size_t)(NIN + kk) * NH + 4*cb + c];
            w4[c][j].x = base[0*NH];
            w4[c][j].y = base[1*NH];
            w4[c][j].z = base[2*NH];
            w4[c][j].w = base[3*NH];
        }
    }
    // Launder: values become opaque asm results -> must stay resident.
    #pragma unroll
    for (int c = 0; c < 4; c++)
        #pragma unroll
        for (int j = 0; j < 8; j++)
            asm volatile("" : "+v"(w4[c][j].x), "+v"(w4[c][j].y),
                             "+v"(w4[c][j].z), "+v"(w4[c][j].w));

    if (tid < NH) hbuf[0][tid] = h0[b*NH + tid];
    float xc = xp[(size_t)(0*BATCH + b) * NH + colf];
    __syncthreads();

    for (int t = 0; t < SEQ; t++) {
        const float* rb = &hbuf[t & 1][32 * kb];
        float xn = 0.f;
        if (t + 1 < SEQ) xn = xp[(size_t)((t+1)*BATCH + b) * NH + colf];

        // load h chunk (bank-staggered) and FMA into 4 column accumulators
        float4 hv[8];
        #pragma unroll
        for (int j = 0; j < 8; j++)
            hv[j] = *(const float4*)&rb[4 * ((j + kb) & 7)];

        float a0 = 0.f, a1 = 0.f, a2 = 0.f, a3 = 0.f;
        #pragma unroll
        for (int j = 0; j < 8; j++) {
            a0 = fmaf(hv[j].x, w4[0][j].x, a0); a0 = fmaf(hv[j].y, w4[0][j].y, a0);
            a0 = fmaf(hv[j].z, w4[0][j].z, a0); a0 = fmaf(hv[j].w, w4[0][j].w, a0);
            a1 = fmaf(hv[j].x, w4[1][j].x, a1); a1 = fmaf(hv[j].y, w4[1][j].y, a1);
            a1 = fmaf(hv[j].z, w4[1][j].z, a1); a1 = fmaf(hv[j].w, w4[1][j].w, a1);
            a2 = fmaf(hv[j].x, w4[2][j].x, a2); a2 = fmaf(hv[j].y, w4[2][j].y, a2);
            a2 = fmaf(hv[j].z, w4[2][j].z, a2); a2 = fmaf(hv[j].w, w4[2][j].w, a2);
            a3 = fmaf(hv[j].x, w4[3][j].x, a3); a3 = fmaf(hv[j].y, w4[3][j].y, a3);
            a3 = fmaf(hv[j].z, w4[3][j].z, a3); a3 = fmaf(hv[j].w, w4[3][j].w, a3);
        }

        // select-fold reduction over kb lanes (xor 1, 2, 4) — 4 shfls
        bool s0 = (kb & 1) != 0, s1 = (kb & 2) != 0;
        float k0v = s0 ? a2 : a0, k1v = s0 ? a3 : a1;
        float d0  = s0 ? a0 : a2, d1  = s0 ? a1 : a3;
        k0v += __shfl_xor(d0, 1, 64);
        k1v += __shfl_xor(d1, 1, 64);
        float ke = s1 ? k1v : k0v;
        float de = s1 ? k0v : k1v;
        ke += __shfl_xor(de, 2, 64);
        ke += __shfl_xor(ke, 4, 64);

        float s = ke + xc;
        // tanh via (z-1)/(z+1), z = exp2(2*log2(e)*s)
        float arg = s * 2.88539004f;
        float z;
        asm("v_exp_f32 %0, %1" : "=v"(z) : "v"(arg));
        float inv;
        float den = z + 1.0f;
        asm("v_rcp_f32 %0, %1" : "=v"(inv) : "v"(den));
        float hn = (z - 1.0f) * inv;

        if ((kb & 4) == 0) hbuf[(t + 1) & 1][colf] = hn;               // LDS for next step
        else               hs[(size_t)(t*BATCH + b) * NH + colf] = hn; // global, stays in flight
        xc = xn;

        asm volatile("s_waitcnt lgkmcnt(0)" ::: "memory");
        __builtin_amdgcn_s_barrier();
        asm volatile("" ::: "memory");
    }
}

// ---------------- K3: out = hs @ W_h2o + b_h2o ----------------
__global__ __launch_bounds__(256) void k_out(const float* __restrict__ hs,
                                             const float* __restrict__ Wh2o,
                                             const float* __restrict__ bh2o,
                                             float* __restrict__ out) {
    __shared__ float Wl[NH][64];
    __shared__ float Hl[8][NH];
    int bid = blockIdx.x;
    int half = bid & 1;
    int rt = bid >> 1;
    int tid = threadIdx.x;

    for (int i = tid; i < NH*64; i += 256) {
        int k = i >> 6, o = i & 63;
        Wl[k][o] = Wh2o[(size_t)k*NOUT + half*64 + o];
    }
    int o = tid & 63, g = tid >> 6;
    float bias = bh2o[half*64 + o];

    for (int tile = 0; tile < 16; tile++) {
        int r0 = rt*128 + tile*8;
        __syncthreads();
        for (int i = tid; i < 8*NH; i += 256)
            Hl[i >> 8][i & 255] = hs[(size_t)r0*NH + i];
        __syncthreads();
        float a0 = 0.f, a1 = 0.f;
        int r = g * 2;
        #pragma unroll 8
        for (int k = 0; k < NH; k++) {
            float wv = Wl[k][o];
            a0 = fmaf(Hl[r][k],   wv, a0);
            a1 = fmaf(Hl[r+1][k], wv, a1);
        }
        out[(size_t)(r0 + r)     * NOUT + half*64 + o] = a0 + bias;
        out[(size_t)(r0 + r + 1) * NOUT + half*64 + o] = a1 + bias;
    }
}

extern "C" void kernel_launch(void* const* d_in, const int* in_sizes, int n_in,
                              void* d_out, int out_size, void* d_ws, size_t ws_size,
                              hipStream_t stream) {
    const float* x    = (const float*)d_in[0];
    const float* h0   = (const float*)d_in[1];
    const float* Wi2h = (const float*)d_in[2];
    const float* bi2h = (const float*)d_in[3];
    const float* Wh2o = (const float*)d_in[4];
    const float* bh2o = (const float*)d_in[5];
    float* out = (float*)d_out;

    float* xp = (float*)d_ws;                     // M*NH f32 = 32 MB
    float* hs = xp + (size_t)M * NH;              // M*NH f32 = 32 MB

    k_xproj<<<dim3(2048), dim3(256), 0, stream>>>(x, Wi2h, bi2h, xp);
    k_scan <<<dim3(BATCH), dim3(512), 0, stream>>>(Wi2h, h0, xp, hs);
    k_out  <<<dim3(512), dim3(256), 0, stream>>>(hs, Wh2o, bh2o, out);
}